// Round 10
// baseline (651.875 us; speedup 1.0000x reference)
//
#include <hip/hip_runtime.h>
#include <hip/hip_bf16.h>
#include <hip/hip_cooperative_groups.h>

namespace cg = cooperative_groups;

// Batched COO SpMM: out[k, row[e], f] = sum_e values[k][e] * b[k][col[e]][f]
// B=4, NNZ=800000, M=N=50000, F=64.
//
// Round 10: ALL preprocessing fused into ONE cooperative kernel with
// grid.sync() phase boundaries (kills 5 launch gaps, overlaps the 77MB
// b->bf16 stream with the latency-bound permute phase, and makes prep cost
// visible as a single dispatch in the profile).
// Phases: P0 zero counts | P1 hist | P2 block partial sums | P3 scan block
// sums (block 0) | P4 apply -> row_ptr/cursor | P5 permute-pack + transform.
// SpMM unchanged from R9 (71.7us proven): one uint4 edge record + one
// contiguous 512B bf16 gather per edge.

#define FEAT 64
#define SCAN_CHUNK 1024
#define COOP_BLOCKS 1024
#define COOP_THREADS 256

__device__ inline unsigned f2bf(float x) {
    unsigned u = __float_as_uint(x);
    return (u + 0x7FFFu + ((u >> 16) & 1u)) >> 16;   // round-nearest-even
}

// ---------- cooperative preprocessing ----------
__global__ __launch_bounds__(COOP_THREADS) void prep_coop_kernel(
    const int* __restrict__ indices, const float* __restrict__ values,
    const float* __restrict__ b,
    int* __restrict__ counts, int* __restrict__ row_ptr,
    int* __restrict__ cursor, int* __restrict__ blocksum,
    int* __restrict__ blockoff, uint4* __restrict__ edges,
    unsigned short* __restrict__ b16, int m, int nnz, int nblk) {
    cg::grid_group grid = cg::this_grid();
    const int t = threadIdx.x;
    const int gtid = blockIdx.x * COOP_THREADS + t;
    const int gsize = COOP_BLOCKS * COOP_THREADS;
    __shared__ int bufA[COOP_THREADS];
    __shared__ int bufB[COOP_THREADS];

    // P0: zero counts
    for (int i = gtid; i < m; i += gsize) counts[i] = 0;
    grid.sync();

    // P1: histogram of rows (fire-and-forget atomics)
    for (int i = gtid; i < nnz; i += gsize)
        atomicAdd(&counts[indices[i]], 1);
    grid.sync();

    // P2: per-block partial sums of SCAN_CHUNK-count chunks
    if (blockIdx.x < nblk) {
        const int g = blockIdx.x * SCAN_CHUNK + t * 4;
        int s = 0;
        if (g + 3 < m) {
            const int4 c = *(const int4*)&counts[g];
            s = c.x + c.y + c.z + c.w;
        } else {
            for (int i = g; i < m; ++i) s += counts[i];
        }
        bufA[t] = s;
        __syncthreads();
        for (int off = 128; off; off >>= 1) {
            if (t < off) bufA[t] += bufA[t + off];
            __syncthreads();
        }
        if (t == 0) blocksum[blockIdx.x] = bufA[0];
    }
    grid.sync();

    // P3: block 0 scans the (<=256) block sums -> exclusive offsets
    if (blockIdx.x == 0) {
        const int v = (t < nblk) ? blocksum[t] : 0;
        bufA[t] = v;
        __syncthreads();
        int* src = bufA;
        int* dst = bufB;
        for (int off = 1; off < 256; off <<= 1) {
            int x = src[t];
            if (t >= off) x += src[t - off];
            dst[t] = x;
            __syncthreads();
            int* tmp = src; src = dst; dst = tmp;
        }
        if (t < nblk) blockoff[t] = src[t] - v;   // exclusive
        if (t == 0) row_ptr[m] = nnz;
    }
    grid.sync();

    // P4: apply -> row_ptr & cursor (int4 writes)
    if (blockIdx.x < nblk) {
        const int g = blockIdx.x * SCAN_CHUNK + t * 4;
        int c0 = 0, c1 = 0, c2 = 0, c3 = 0;
        if (g + 3 < m) {
            const int4 c = *(const int4*)&counts[g];
            c0 = c.x; c1 = c.y; c2 = c.z; c3 = c.w;
        } else {
            if (g < m)     c0 = counts[g];
            if (g + 1 < m) c1 = counts[g + 1];
            if (g + 2 < m) c2 = counts[g + 2];
        }
        const int s = c0 + c1 + c2 + c3;
        bufA[t] = s;
        __syncthreads();
        int* src = bufA;
        int* dst = bufB;
        for (int off = 1; off < 256; off <<= 1) {
            int x = src[t];
            if (t >= off) x += src[t - off];
            dst[t] = x;
            __syncthreads();
            int* tmp = src; src = dst; dst = tmp;
        }
        const int base = src[t] - s + blockoff[blockIdx.x];
        const int p0 = base, p1 = p0 + c0, p2 = p1 + c1, p3 = p2 + c2;
        if (g + 3 < m) {
            const int4 pq = make_int4(p0, p1, p2, p3);
            *(int4*)&row_ptr[g] = pq;
            *(int4*)&cursor[g]  = pq;
        } else {
            if (g < m)     { row_ptr[g]     = p0; cursor[g]     = p0; }
            if (g + 1 < m) { row_ptr[g + 1] = p1; cursor[g + 1] = p1; }
            if (g + 2 < m) { row_ptr[g + 2] = p2; cursor[g + 2] = p2; }
        }
    }
    grid.sync();

    // P5: counting-sort pack (latency/atomic-bound) + b->bf16 transform
    // (bandwidth-bound) -- overlapped in one phase.
    for (int i = gtid; i < nnz; i += gsize) {
        const int r = indices[i];
        const int c = indices[nnz + i];
        const float v0 = values[i];
        const float v1 = values[(size_t)nnz + i];
        const float v2 = values[2 * (size_t)nnz + i];
        const float v3 = values[3 * (size_t)nnz + i];
        uint4 e;
        e.x = (unsigned)c;
        e.y = f2bf(v0) | (f2bf(v1) << 16);
        e.z = f2bf(v2) | (f2bf(v3) << 16);
        e.w = 0;
        const int pos = atomicAdd(&cursor[r], 1);
        edges[pos] = e;
    }
    const int plane = m * 16;             // float4s per batch plane of b
    for (int q = gtid; q < 4 * plane; q += gsize) {
        const float4 v = *(const float4*)(b + (size_t)q * 4);
        const int k   = q / plane;
        const int rem = q - k * plane;
        const int c   = rem >> 4;
        const int f0  = (rem & 15) * 4;
        ushort4 o;
        o.x = (unsigned short)f2bf(v.x);
        o.y = (unsigned short)f2bf(v.y);
        o.z = (unsigned short)f2bf(v.z);
        o.w = (unsigned short)f2bf(v.w);
        *(ushort4*)(b16 + (size_t)c * 256 + k * 64 + f0) = o;
    }
}

// ---------- main SpMM (bf16 gather, packed edges; unchanged from R9) ------
__global__ __launch_bounds__(256) void spmm_csr_bf16_kernel(
    const int* __restrict__ row_ptr, const uint4* __restrict__ edges,
    const unsigned short* __restrict__ b16, float* __restrict__ out, int m) {
    const int lane = threadIdx.x & 63;
    const int wave = blockIdx.x * (blockDim.x >> 6) + (threadIdx.x >> 6);
    if (wave >= m) return;
    const int row   = wave;
    const int start = row_ptr[row];
    const int end   = row_ptr[row + 1];

    const int k  = lane >> 4;
    const int f0 = (lane & 15) * 4;
    const bool khi = (k & 2) != 0;   // use .z word
    const bool kod = (k & 1) != 0;   // use high half
    const unsigned short* __restrict__ bk = b16 + k * 64 + f0;  // + c*256/edge

#define BF(u) __uint_as_float((unsigned)(u) << 16)
#define VSEL(e) __uint_as_float(kod ? ((khi ? e.z : e.y) & 0xFFFF0000u) \
                                    : ((khi ? e.z : e.y) << 16))
    float4 acc = make_float4(0.f, 0.f, 0.f, 0.f);
    int j = start;
    for (; j + 3 < end; j += 4) {
        const uint4 e0 = edges[j];
        const uint4 e1 = edges[j + 1];
        const uint4 e2 = edges[j + 2];
        const uint4 e3 = edges[j + 3];
        const ushort4 u0 = *(const ushort4*)(bk + (size_t)e0.x * 256);
        const ushort4 u1 = *(const ushort4*)(bk + (size_t)e1.x * 256);
        const ushort4 u2 = *(const ushort4*)(bk + (size_t)e2.x * 256);
        const ushort4 u3 = *(const ushort4*)(bk + (size_t)e3.x * 256);
        const float v0 = VSEL(e0);
        const float v1 = VSEL(e1);
        const float v2 = VSEL(e2);
        const float v3 = VSEL(e3);
        acc.x += v0 * BF(u0.x) + v1 * BF(u1.x) + v2 * BF(u2.x) + v3 * BF(u3.x);
        acc.y += v0 * BF(u0.y) + v1 * BF(u1.y) + v2 * BF(u2.y) + v3 * BF(u3.y);
        acc.z += v0 * BF(u0.z) + v1 * BF(u1.z) + v2 * BF(u2.z) + v3 * BF(u3.z);
        acc.w += v0 * BF(u0.w) + v1 * BF(u1.w) + v2 * BF(u2.w) + v3 * BF(u3.w);
    }
    for (; j < end; ++j) {
        const uint4 e = edges[j];
        const ushort4 u = *(const ushort4*)(bk + (size_t)e.x * 256);
        const float v = VSEL(e);
        acc.x += v * BF(u.x);
        acc.y += v * BF(u.y);
        acc.z += v * BF(u.z);
        acc.w += v * BF(u.w);
    }
#undef VSEL
#undef BF
    const size_t bm = (size_t)m * FEAT;
    *(float4*)(out + (size_t)k * bm + (size_t)row * FEAT + f0) = acc;
}

// ---------- fallback (round-1 atomic version) ----------
__global__ __launch_bounds__(256) void spmm_atomic_kernel(
    const int* __restrict__ indices, const float* __restrict__ values,
    const float* __restrict__ b, float* __restrict__ out,
    int nnz, int m, int batch, int ntasks) {
    const int lane = threadIdx.x & 63;
    const int waves_per_block = blockDim.x >> 6;
    const int nwaves = gridDim.x * waves_per_block;
    int wave = blockIdx.x * waves_per_block + (threadIdx.x >> 6);
    for (int task = wave; task < ntasks; task += nwaves) {
        const int e = task / batch;
        const int k = task - e * batch;
        const int row = indices[e];
        const int col = indices[nnz + e];
        const float v = values[(size_t)k * nnz + e];
        const float contrib = v * b[((size_t)k * m + col) * FEAT + lane];
        unsafeAtomicAdd(&out[((size_t)k * m + row) * FEAT + lane], contrib);
    }
}

static inline uintptr_t align16(uintptr_t p) { return (p + 15) & ~(uintptr_t)15; }

extern "C" void kernel_launch(void* const* d_in, const int* in_sizes, int n_in,
                              void* d_out, int out_size, void* d_ws, size_t ws_size,
                              hipStream_t stream) {
    const int* indices  = (const int*)d_in[0];    // [2, nnz]
    const float* values = (const float*)d_in[1];  // [batch, nnz]
    const float* b      = (const float*)d_in[4];  // [batch, m, FEAT]
    float* out          = (float*)d_out;

    int nnz   = in_sizes[0] / 2;
    const int batch = in_sizes[1] / nnz;
    int m     = out_size / (batch * FEAT);
    int nblk  = (m + SCAN_CHUNK - 1) / SCAN_CHUNK;

    // ws layout, each array 16B-aligned:
    uintptr_t p = (uintptr_t)d_ws;
    int* counts      = (int*)align16(p);             p = (uintptr_t)(counts + m);
    int* row_ptr     = (int*)align16(p);             p = (uintptr_t)(row_ptr + m + 1);
    int* cursor      = (int*)align16(p);             p = (uintptr_t)(cursor + m);
    int* blocksum    = (int*)align16(p);             p = (uintptr_t)(blocksum + nblk);
    int* blockoff    = (int*)align16(p);             p = (uintptr_t)(blockoff + nblk);
    uint4* edges     = (uint4*)align16(p);           p = (uintptr_t)(edges + nnz);
    unsigned short* b16 = (unsigned short*)align16(p);
    p = (uintptr_t)(b16 + (size_t)m * 4 * FEAT);
    const size_t need = p - (uintptr_t)d_ws;

    if (batch != 4 || nblk > 256 || ws_size < need) {
        hipMemsetAsync(d_out, 0, (size_t)out_size * sizeof(float), stream);
        spmm_atomic_kernel<<<2048, 256, 0, stream>>>(indices, values, b, out,
                                                     nnz, m, batch, nnz * batch);
        return;
    }

    void* kargs[] = {
        (void*)&indices, (void*)&values, (void*)&b,
        (void*)&counts, (void*)&row_ptr, (void*)&cursor,
        (void*)&blocksum, (void*)&blockoff, (void*)&edges, (void*)&b16,
        (void*)&m, (void*)&nnz, (void*)&nblk
    };
    hipLaunchCooperativeKernel((const void*)prep_coop_kernel,
                               dim3(COOP_BLOCKS), dim3(COOP_THREADS),
                               kargs, 0, stream);

    const int waves_per_block = 4;  // 256 threads
    const int grid = (m + waves_per_block - 1) / waves_per_block;
    spmm_csr_bf16_kernel<<<grid, 256, 0, stream>>>(row_ptr, edges, b16,
                                                   out, m);
}

// Round 11
// 179.596 us; speedup vs baseline: 3.6297x; 3.6297x over previous
//
#include <hip/hip_runtime.h>
#include <hip/hip_bf16.h>

// Batched COO SpMM: out[k, row[e], f] = sum_e values[k][e] * b[k][col[e]][f]
// B=4, NNZ=800000, M=N=50000, F=64.
//
// Round 11 = R9 structure (cooperative fusion in R10 regressed 3.5x: ROCm
// grid.sync costs ~100us/sync at 1024 blocks -- separate graph-replayed
// launches are far cheaper). Prep tweaks vs R9:
//  - scan_block merged into scan_apply (each block redundantly scans the
//    <=256 block sums in LDS; one fewer launch)
//  - hist/permute at 2048 blocks (2x resident threads, more MLP)
//  - permute processes edge PAIRS: coalesced int2/float2 reads, two
//    independent atomic claims then two scatters (breaks atomic->store chain)
//  - hist reads rows as int4, fires 4 independent atomics
// SpMM unchanged from R9 (71.7us proven): one uint4 edge record + one
// contiguous 512B bf16 gather per edge; b16 transform rides the hist launch.

#define FEAT 64
#define SCAN_CHUNK 1024
#define HIST_BLOCKS 2048
#define PERM_BLOCKS 2048

__device__ inline unsigned f2bf(float x) {
    unsigned u = __float_as_uint(x);
    return (u + 0x7FFFu + ((u >> 16) & 1u)) >> 16;   // round-nearest-even
}

// ---------- preprocessing ----------

// Blocks [0,HIST_BLOCKS): histogram rows (int4 reads, 4 independent atomics).
// Blocks >= HIST_BLOCKS: stream-convert b [4][m][64] fp32 -> b16 [m][4][64].
__global__ void hist_transform_kernel(const int* __restrict__ rows,
                                      int* __restrict__ counts, int nnz,
                                      const float* __restrict__ b,
                                      unsigned short* __restrict__ b16, int m) {
    if (blockIdx.x < HIST_BLOCKS) {
        const int stride = HIST_BLOCKS * blockDim.x * 4;
        for (int i = (blockIdx.x * blockDim.x + threadIdx.x) * 4; i < nnz;
             i += stride) {
            if (i + 3 < nnz) {
                const int4 r = *(const int4*)&rows[i];
                atomicAdd(&counts[r.x], 1);
                atomicAdd(&counts[r.y], 1);
                atomicAdd(&counts[r.z], 1);
                atomicAdd(&counts[r.w], 1);
            } else {
                for (int q = i; q < nnz; ++q) atomicAdd(&counts[rows[q]], 1);
            }
        }
    } else {
        const int q = (blockIdx.x - HIST_BLOCKS) * blockDim.x + threadIdx.x;
        const int plane = m * 16;             // float4s per batch plane
        if (q < 4 * plane) {
            const float4 v = *(const float4*)(b + (size_t)q * 4);
            const int k   = q / plane;
            const int rem = q - k * plane;
            const int c   = rem >> 4;
            const int f0  = (rem & 15) * 4;
            ushort4 o;
            o.x = (unsigned short)f2bf(v.x);
            o.y = (unsigned short)f2bf(v.y);
            o.z = (unsigned short)f2bf(v.z);
            o.w = (unsigned short)f2bf(v.w);
            *(ushort4*)(b16 + (size_t)c * 256 + k * 64 + f0) = o;
        }
    }
}

// S1: per-block sum of a 1024-count chunk (coalesced int4 reads).
__global__ __launch_bounds__(256) void scan_partial_kernel(
    const int* __restrict__ counts, int* __restrict__ blocksum, int m) {
    __shared__ int red[256];
    const int t = threadIdx.x;
    const int g = blockIdx.x * SCAN_CHUNK + t * 4;
    int s = 0;
    if (g + 3 < m) {
        const int4 c = *(const int4*)&counts[g];
        s = c.x + c.y + c.z + c.w;
    } else {
        for (int i = g; i < m; ++i) s += counts[i];
    }
    red[t] = s;
    __syncthreads();
    for (int off = 128; off; off >>= 1) {
        if (t < off) red[t] += red[t + off];
        __syncthreads();
    }
    if (t == 0) blocksum[blockIdx.x] = red[0];
}

// S2 (merged): every block scans the <=256 blocksums in LDS to get its own
// exclusive offset, then scans its chunk and writes row_ptr & cursor.
__global__ __launch_bounds__(256) void scan_apply_kernel(
    const int* __restrict__ counts, const int* __restrict__ blocksum,
    int* __restrict__ row_ptr, int* __restrict__ cursor, int m, int nnz,
    int nblk) {
    __shared__ int bufA[256];
    __shared__ int bufB[256];
    const int t = threadIdx.x;

    // scan block sums (redundant per block; 49 ints -> trivial)
    const int bv = (t < nblk) ? blocksum[t] : 0;
    bufA[t] = bv;
    __syncthreads();
    int* src = bufA;
    int* dst = bufB;
    for (int off = 1; off < 256; off <<= 1) {
        int x = src[t];
        if (t >= off) x += src[t - off];
        dst[t] = x;
        __syncthreads();
        int* tmp = src; src = dst; dst = tmp;
    }
    const int blockoff = (blockIdx.x == 0) ? 0 : src[blockIdx.x - 1];
    __syncthreads();

    // per-chunk scan + apply
    const int g = blockIdx.x * SCAN_CHUNK + t * 4;
    int c0 = 0, c1 = 0, c2 = 0, c3 = 0;
    if (g + 3 < m) {
        const int4 c = *(const int4*)&counts[g];
        c0 = c.x; c1 = c.y; c2 = c.z; c3 = c.w;
    } else {
        if (g < m)     c0 = counts[g];
        if (g + 1 < m) c1 = counts[g + 1];
        if (g + 2 < m) c2 = counts[g + 2];
    }
    const int s = c0 + c1 + c2 + c3;
    bufA[t] = s;
    __syncthreads();
    src = bufA;
    dst = bufB;
    for (int off = 1; off < 256; off <<= 1) {
        int x = src[t];
        if (t >= off) x += src[t - off];
        dst[t] = x;
        __syncthreads();
        int* tmp = src; src = dst; dst = tmp;
    }
    const int base = src[t] - s + blockoff;
    const int p0 = base, p1 = p0 + c0, p2 = p1 + c1, p3 = p2 + c2;
    if (g + 3 < m) {
        const int4 pq = make_int4(p0, p1, p2, p3);
        *(int4*)&row_ptr[g] = pq;
        *(int4*)&cursor[g]  = pq;
    } else {
        if (g < m)     { row_ptr[g]     = p0; cursor[g]     = p0; }
        if (g + 1 < m) { row_ptr[g + 1] = p1; cursor[g + 1] = p1; }
        if (g + 2 < m) { row_ptr[g + 2] = p2; cursor[g + 2] = p2; }
    }
    if (blockIdx.x == 0 && t == 0) row_ptr[m] = nnz;
}

// Counting sort: each thread owns a contiguous PAIR of edges (coalesced
// int2/float2 reads), fires both independent atomics, then both 16B scatters.
__global__ void permute_pack_kernel(const int* __restrict__ indices,
                                    const float* __restrict__ values,
                                    int* __restrict__ cursor,
                                    uint4* __restrict__ edges, int nnz) {
    const int stride = PERM_BLOCKS * blockDim.x * 2;
    for (int i = (blockIdx.x * blockDim.x + threadIdx.x) * 2; i < nnz;
         i += stride) {
        if (i + 1 < nnz) {
            const int2 r  = *(const int2*)&indices[i];
            const int2 c  = *(const int2*)&indices[nnz + i];
            const float2 w0 = *(const float2*)&values[i];
            const float2 w1 = *(const float2*)&values[(size_t)nnz + i];
            const float2 w2 = *(const float2*)&values[2 * (size_t)nnz + i];
            const float2 w3 = *(const float2*)&values[3 * (size_t)nnz + i];
            uint4 e0, e1;
            e0.x = (unsigned)c.x;
            e0.y = f2bf(w0.x) | (f2bf(w1.x) << 16);
            e0.z = f2bf(w2.x) | (f2bf(w3.x) << 16);
            e0.w = 0;
            e1.x = (unsigned)c.y;
            e1.y = f2bf(w0.y) | (f2bf(w1.y) << 16);
            e1.z = f2bf(w2.y) | (f2bf(w3.y) << 16);
            e1.w = 0;
            const int p0 = atomicAdd(&cursor[r.x], 1);
            const int p1 = atomicAdd(&cursor[r.y], 1);
            edges[p0] = e0;
            edges[p1] = e1;
        } else {
            const int r = indices[i];
            const int c = indices[nnz + i];
            uint4 e;
            e.x = (unsigned)c;
            e.y = f2bf(values[i]) | (f2bf(values[(size_t)nnz + i]) << 16);
            e.z = f2bf(values[2 * (size_t)nnz + i]) |
                  (f2bf(values[3 * (size_t)nnz + i]) << 16);
            e.w = 0;
            const int p = atomicAdd(&cursor[r], 1);
            edges[p] = e;
        }
    }
}

// ---------- main SpMM (bf16 gather, packed edges; unchanged from R9) ------
__global__ __launch_bounds__(256) void spmm_csr_bf16_kernel(
    const int* __restrict__ row_ptr, const uint4* __restrict__ edges,
    const unsigned short* __restrict__ b16, float* __restrict__ out, int m) {
    const int lane = threadIdx.x & 63;
    const int wave = blockIdx.x * (blockDim.x >> 6) + (threadIdx.x >> 6);
    if (wave >= m) return;
    const int row   = wave;
    const int start = row_ptr[row];
    const int end   = row_ptr[row + 1];

    const int k  = lane >> 4;
    const int f0 = (lane & 15) * 4;
    const bool khi = (k & 2) != 0;   // use .z word
    const bool kod = (k & 1) != 0;   // use high half
    const unsigned short* __restrict__ bk = b16 + k * 64 + f0;  // + c*256/edge

#define BF(u) __uint_as_float((unsigned)(u) << 16)
#define VSEL(e) __uint_as_float(kod ? ((khi ? e.z : e.y) & 0xFFFF0000u) \
                                    : ((khi ? e.z : e.y) << 16))
    float4 acc = make_float4(0.f, 0.f, 0.f, 0.f);
    int j = start;
    for (; j + 3 < end; j += 4) {
        const uint4 e0 = edges[j];
        const uint4 e1 = edges[j + 1];
        const uint4 e2 = edges[j + 2];
        const uint4 e3 = edges[j + 3];
        const ushort4 u0 = *(const ushort4*)(bk + (size_t)e0.x * 256);
        const ushort4 u1 = *(const ushort4*)(bk + (size_t)e1.x * 256);
        const ushort4 u2 = *(const ushort4*)(bk + (size_t)e2.x * 256);
        const ushort4 u3 = *(const ushort4*)(bk + (size_t)e3.x * 256);
        const float v0 = VSEL(e0);
        const float v1 = VSEL(e1);
        const float v2 = VSEL(e2);
        const float v3 = VSEL(e3);
        acc.x += v0 * BF(u0.x) + v1 * BF(u1.x) + v2 * BF(u2.x) + v3 * BF(u3.x);
        acc.y += v0 * BF(u0.y) + v1 * BF(u1.y) + v2 * BF(u2.y) + v3 * BF(u3.y);
        acc.z += v0 * BF(u0.z) + v1 * BF(u1.z) + v2 * BF(u2.z) + v3 * BF(u3.z);
        acc.w += v0 * BF(u0.w) + v1 * BF(u1.w) + v2 * BF(u2.w) + v3 * BF(u3.w);
    }
    for (; j < end; ++j) {
        const uint4 e = edges[j];
        const ushort4 u = *(const ushort4*)(bk + (size_t)e.x * 256);
        const float v = VSEL(e);
        acc.x += v * BF(u.x);
        acc.y += v * BF(u.y);
        acc.z += v * BF(u.z);
        acc.w += v * BF(u.w);
    }
#undef VSEL
#undef BF
    const size_t bm = (size_t)m * FEAT;
    *(float4*)(out + (size_t)k * bm + (size_t)row * FEAT + f0) = acc;
}

// ---------- fallback (round-1 atomic version) ----------
__global__ __launch_bounds__(256) void spmm_atomic_kernel(
    const int* __restrict__ indices, const float* __restrict__ values,
    const float* __restrict__ b, float* __restrict__ out,
    int nnz, int m, int batch, int ntasks) {
    const int lane = threadIdx.x & 63;
    const int waves_per_block = blockDim.x >> 6;
    const int nwaves = gridDim.x * waves_per_block;
    int wave = blockIdx.x * waves_per_block + (threadIdx.x >> 6);
    for (int task = wave; task < ntasks; task += nwaves) {
        const int e = task / batch;
        const int k = task - e * batch;
        const int row = indices[e];
        const int col = indices[nnz + e];
        const float v = values[(size_t)k * nnz + e];
        const float contrib = v * b[((size_t)k * m + col) * FEAT + lane];
        unsafeAtomicAdd(&out[((size_t)k * m + row) * FEAT + lane], contrib);
    }
}

static inline uintptr_t align16(uintptr_t p) { return (p + 15) & ~(uintptr_t)15; }

extern "C" void kernel_launch(void* const* d_in, const int* in_sizes, int n_in,
                              void* d_out, int out_size, void* d_ws, size_t ws_size,
                              hipStream_t stream) {
    const int* indices  = (const int*)d_in[0];    // [2, nnz]
    const float* values = (const float*)d_in[1];  // [batch, nnz]
    const float* b      = (const float*)d_in[4];  // [batch, m, FEAT]
    float* out          = (float*)d_out;

    const int nnz   = in_sizes[0] / 2;
    const int batch = in_sizes[1] / nnz;
    const int m     = out_size / (batch * FEAT);
    const int nblk  = (m + SCAN_CHUNK - 1) / SCAN_CHUNK;

    // ws layout, each array 16B-aligned:
    uintptr_t p = (uintptr_t)d_ws;
    int* counts      = (int*)align16(p);             p = (uintptr_t)(counts + m);
    int* row_ptr     = (int*)align16(p);             p = (uintptr_t)(row_ptr + m + 1);
    int* cursor      = (int*)align16(p);             p = (uintptr_t)(cursor + m);
    int* blocksum    = (int*)align16(p);             p = (uintptr_t)(blocksum + nblk);
    uint4* edges     = (uint4*)align16(p);           p = (uintptr_t)(edges + nnz);
    unsigned short* b16 = (unsigned short*)align16(p);
    p = (uintptr_t)(b16 + (size_t)m * 4 * FEAT);
    const size_t need = p - (uintptr_t)d_ws;

    if (batch != 4 || nblk > 256 || ws_size < need) {
        hipMemsetAsync(d_out, 0, (size_t)out_size * sizeof(float), stream);
        spmm_atomic_kernel<<<2048, 256, 0, stream>>>(indices, values, b, out,
                                                     nnz, m, batch, nnz * batch);
        return;
    }

    hipMemsetAsync(counts, 0, (size_t)m * sizeof(int), stream);
    const int tblocks = (m * FEAT + 255) / 256;   // all float4s of b
    hist_transform_kernel<<<HIST_BLOCKS + tblocks, 256, 0, stream>>>(
        indices, counts, nnz, b, b16, m);
    scan_partial_kernel<<<nblk, 256, 0, stream>>>(counts, blocksum, m);
    scan_apply_kernel<<<nblk, 256, 0, stream>>>(counts, blocksum,
                                                row_ptr, cursor, m, nnz, nblk);
    permute_pack_kernel<<<PERM_BLOCKS, 256, 0, stream>>>(indices, values,
                                                         cursor, edges, nnz);

    const int waves_per_block = 4;  // 256 threads
    const int grid = (m + waves_per_block - 1) / waves_per_block;
    spmm_csr_bf16_kernel<<<grid, 256, 0, stream>>>(row_ptr, edges, b16,
                                                   out, m);
}